// Round 15
// baseline (105.394 us; speedup 1.0000x reference)
//
#include <hip/hip_runtime.h>
#include <math.h>

#define B_ 4
#define T_ 64
#define N_ 2048
#define C_ 32
#define H_ 64
#define M_ (B_*N_)      // 8192
#define SLOPE 0.2f
#define LOG2E 1.44269504088896340736f

typedef __attribute__((ext_vector_type(8))) _Float16 half8;  // 8 f16 (4 VGPRs)
typedef __attribute__((ext_vector_type(4))) float floatx4;   // MFMA acc

#define MFMA16H(a,b,c) __builtin_amdgcn_mfma_f32_16x16x32_f16(a,b,c,0,0,0)

// Single-wave LDS fence: no s_barrier anywhere in the kernel. Writes and the
// dependent cross-lane reads belong to the SAME wave; lgkmcnt(0) guarantees
// the writes completed before subsequent reads issue.
#define FENCE() asm volatile("s_waitcnt lgkmcnt(0)" ::: "memory")

__device__ __forceinline__ float lrelu(float v) { return fmaxf(v, SLOPE * v); }
__device__ __forceinline__ float frcp(float x)  { return __builtin_amdgcn_rcpf(x); }
__device__ __forceinline__ float fexp2(float x) { float r; asm("v_exp_f32 %0, %1" : "=v"(r) : "v"(x)); return r; }

__device__ __forceinline__ half8 cvt8h(float4 a, float4 b) {
    half8 h;
    h[0]=(_Float16)a.x; h[1]=(_Float16)a.y; h[2]=(_Float16)a.z; h[3]=(_Float16)a.w;
    h[4]=(_Float16)b.x; h[5]=(_Float16)b.y; h[6]=(_Float16)b.z; h[7]=(_Float16)b.w;
    return h;
}
__device__ __forceinline__ half8 cvt8s(const float* f, float sc) {
    half8 h;
    #pragma unroll
    for (int e = 0; e < 8; ++e) h[e] = (_Float16)(f[e] * sc);
    return h;
}

// ---------------- GRU kernel: ONE WAVE owns 16 samples x all 64 dims --------
// 512 blocks x 64 threads = 2 independent waves/CU (separate SIMDs).
// NO barriers: h exchange is wave-internal through 4 KB LDS + lgkmcnt fence.
// Per step: 24 h-MFMA (3 gates x 4 col-tiles x 2 kb) + 12 x-MFMA (shadowed:
// R/Z before act, NI after act to avoid WAR on xNI), 16 acts/lane.
// h recurrence fp32 in registers; LDS copy fp16 [2][16][64], swizzle
// col ^ ((row>>2)<<4). Weights fp16 (gate scales folded), all in VGPRs.
__global__ __launch_bounds__(64, 1) void gru_kernel(
    const float* __restrict__ x,      // [B,T,N,C]
    const float* __restrict__ w_ih,   // [192][32]
    const float* __restrict__ w_hh,   // [192][64]
    const float* __restrict__ b_ih,   // [192]
    const float* __restrict__ b_hh,   // [192]
    const float* __restrict__ wk_p,   // [64]
    const float* __restrict__ wq_p,   // [64]
    float* __restrict__ key,          // [M]  (log2e-scaled)
    float* __restrict__ query)        // [M]  (log2e-scaled)
{
    __shared__ __align__(16) _Float16 hh[2][16][64];   // 4 KB

    const int lane = threadIdx.x;      // 0..63
    const int c  = lane & 15;          // col-in-tile / sample-row for A-reads
    const int kg = lane >> 4;          // 0..3

    const int m0 = blockIdx.x * 16;
    const int b  = m0 >> 11;
    const int n0 = m0 & 2047;

    // Gate scales folded into weights/biases:
    //  r: -log2e (r = rcp(1+exp2(aR))); z: +log2e (1-z = rcp(1+exp2(aZ)));
    //  n: 2*log2e (tanh(v) = 1-2*rcp(1+exp2(2*log2e*v)))
    const float gsc[3] = {-LOG2E, LOG2E, 2.f*LOG2E};

    // Weight B-fragments for ALL 64 cols: B[k][col]=w[col][k]
    half8 whhF[3][2][4];   // [gate][kb][col-tile]
    half8 wihF[3][4];      // [gate][col-tile]
    #pragma unroll
    for (int gt = 0; gt < 3; ++gt)
        #pragma unroll
        for (int n = 0; n < 4; ++n) {
            const int rw = gt*64 + n*16 + c;
            #pragma unroll
            for (int kb = 0; kb < 2; ++kb)
                whhF[gt][kb][n] = cvt8s(w_hh + rw*64 + kb*32 + kg*8, gsc[gt]);
            wihF[gt][n] = cvt8s(w_ih + rw*32 + kg*8, gsc[gt]);
        }

    floatx4 bR4[4], bZ4[4], bNI4[4], bNH4[4];
    float wkj[4], wqj[4];
    #pragma unroll
    for (int n = 0; n < 4; ++n) {
        const int j = n*16 + c;
        const float br  = -LOG2E     * (b_ih[j]    + b_hh[j]);
        const float bz  =  LOG2E     * (b_ih[64+j] + b_hh[64+j]);
        const float bin =  2.f*LOG2E * b_ih[128+j];
        const float bhn =  2.f*LOG2E * b_hh[128+j];
        bR4[n]  = (floatx4){br, br, br, br};
        bZ4[n]  = (floatx4){bz, bz, bz, bz};
        bNI4[n] = (floatx4){bin, bin, bin, bin};
        bNH4[n] = (floatx4){bhn, bhn, bhn, bhn};
        wkj[n] = wk_p[j] * LOG2E;
        wqj[n] = wq_p[j] * LOG2E;
    }

    // per-lane x source: sample row = c, channels kg*8..+7
    const float* xlane = x + ((size_t)b*T_*N_ + (n0 + c))*C_ + kg*8;
    const int xstride = N_*C_;

    // zero h buf0 (this wave's own writes; fenced below)
    #pragma unroll
    for (int i = 0; i < 8; ++i)
        ((int*)&hh[0][0][0])[lane + i*64] = 0;

    // ---- prologue: x-phase for step 0; prefetch x(1) ----
    floatx4 xR[4], xZ[4], xNI[4];
    {
        const half8 ax = cvt8h(*(const float4*)xlane, *(const float4*)(xlane + 4));
        #pragma unroll
        for (int n = 0; n < 4; ++n) {
            xR[n]  = MFMA16H(ax, wihF[0][n], bR4[n]);
            xZ[n]  = MFMA16H(ax, wihF[1][n], bZ4[n]);
            xNI[n] = MFMA16H(ax, wihF[2][n], bNI4[n]);
        }
    }
    float4 pAa = *(const float4*)(xlane + xstride);      // x(1) in flight
    float4 pAb = *(const float4*)(xlane + xstride + 4);
    float4 pBa = {0,0,0,0}, pBb = {0,0,0,0};
    FENCE();

    float hp[4][4];                     // [col-tile][row] fp32 recurrence
    #pragma unroll
    for (int n = 0; n < 4; ++n)
        #pragma unroll
        for (int s = 0; s < 4; ++s) hp[n][s] = 0.f;

#define GRU_STEP(T, CUR, FXa, FXb, GXa, GXb) do {                               \
    const int nxt_ = (CUR) ^ 1;                                                 \
    half8 ah[2];                                                                \
    _Pragma("unroll")                                                           \
    for (int kb = 0; kb < 2; ++kb) {                                            \
        const int ke = (kg*8 + kb*32) ^ ((c >> 2) << 4);                        \
        ah[kb] = *(const half8*)&hh[CUR][c][ke];                                \
    }                                                                           \
    /* h-phase: 24 MFMAs; r/z seeded from x-accs (free combine) */              \
    floatx4 aR[4], aZ[4], aNH[4];                                               \
    _Pragma("unroll")                                                           \
    for (int n = 0; n < 4; ++n) {                                               \
        aR[n]  = MFMA16H(ah[0], whhF[0][0][n], xR[n]);                          \
        aZ[n]  = MFMA16H(ah[0], whhF[1][0][n], xZ[n]);                          \
        aNH[n] = MFMA16H(ah[0], whhF[2][0][n], bNH4[n]);                        \
    }                                                                           \
    _Pragma("unroll")                                                           \
    for (int n = 0; n < 4; ++n) {                                               \
        aR[n]  = MFMA16H(ah[1], whhF[0][1][n], aR[n]);                          \
        aZ[n]  = MFMA16H(ah[1], whhF[1][1][n], aZ[n]);                          \
        aNH[n] = MFMA16H(ah[1], whhF[2][1][n], aNH[n]);                         \
    }                                                                           \
    /* x-phase (T+1) part 1: R/Z only (xNI(T) still live for act) */            \
    half8 ax_;                                                                  \
    if ((T) + 1 < T_) {                                                         \
        ax_ = cvt8h(FXa, FXb);                                                  \
        _Pragma("unroll")                                                       \
        for (int n = 0; n < 4; ++n) {                                           \
            xR[n] = MFMA16H(ax_, wihF[0][n], bR4[n]);                           \
            xZ[n] = MFMA16H(ax_, wihF[1][n], bZ4[n]);                           \
        }                                                                       \
    }                                                                           \
    if ((T) + 2 < T_) {  /* issue load x(T+2) */                                \
        GXa = *(const float4*)(xlane + (size_t)((T)+2) * xstride);              \
        GXb = *(const float4*)(xlane + (size_t)((T)+2) * xstride + 4);          \
    }                                                                           \
    /* activations (16/lane) + fp16 h store (2-way banks = free) */             \
    _Pragma("unroll")                                                           \
    for (int n = 0; n < 4; ++n) {                                               \
        _Pragma("unroll")                                                       \
        for (int s = 0; s < 4; ++s) {                                           \
            const float tr = frcp(1.f + fexp2(aR[n][s]));     /* = r   */       \
            const float v  = fmaf(tr, aNH[n][s], xNI[n][s]);                    \
            const float tn = frcp(1.f + fexp2(v));                              \
            const float nn = fmaf(tn, -2.f, 1.f);             /* tanh */        \
            const float tw = frcp(1.f + fexp2(aZ[n][s]));     /* = 1-z */       \
            const float h  = fmaf(tw, nn - hp[n][s], hp[n][s]);                 \
            hp[n][s] = h;                                                       \
            const int m = kg*4 + s;                                             \
            hh[nxt_][m][(n ^ kg)*16 + c] = (_Float16)h;   /* j^((m>>2)<<4) */   \
        }                                                                       \
    }                                                                           \
    /* x-phase (T+1) part 2: NI (overlaps store drain / next ds_read) */        \
    if ((T) + 1 < T_) {                                                         \
        _Pragma("unroll")                                                       \
        for (int n = 0; n < 4; ++n)                                             \
            xNI[n] = MFMA16H(ax_, wihF[2][n], bNI4[n]);                         \
    }                                                                           \
    FENCE();                                                                    \
} while (0)

    for (int t = 0; t < T_; t += 2) {
        GRU_STEP(t,     0, pAa, pAb, pBa, pBb);
        GRU_STEP(t + 1, 1, pBa, pBb, pAa, pAb);
    }
#undef GRU_STEP

    // ---- fused key/query projection (wave-internal, no LDS) ----
    float kp[4], qp[4];
    #pragma unroll
    for (int s = 0; s < 4; ++s) {
        float kv = 0.f, qv = 0.f;
        #pragma unroll
        for (int n = 0; n < 4; ++n) {
            kv = fmaf(hp[n][s], wkj[n], kv);
            qv = fmaf(hp[n][s], wqj[n], qv);
        }
        kp[s] = kv; qp[s] = qv;
    }
    #pragma unroll
    for (int mask = 8; mask; mask >>= 1) {
        #pragma unroll
        for (int s = 0; s < 4; ++s) {
            kp[s] += __shfl_xor(kp[s], mask);
            qp[s] += __shfl_xor(qp[s], mask);
        }
    }
    if (c == 0) {
        #pragma unroll
        for (int s = 0; s < 4; ++s) {
            key  [m0 + kg*4 + s] = kp[s];
            query[m0 + kg*4 + s] = qp[s];
        }
    }
}

// den stores rcp(sum_j exp2(lrelu(ki+qj))).  No max-shift needed: scores are
// small (|k|,|q| <~ 2) -> exp2 args far inside fp32 range.
__global__ __launch_bounds__(256) void den_kernel(
    const float* __restrict__ key, const float* __restrict__ query,
    float* __restrict__ den)
{
    int idx  = (blockIdx.x * 256 + threadIdx.x) >> 6;   // b*2048 + i
    int lane = threadIdx.x & 63;
    int b    = idx >> 11;
    float ki = key[idx];
    const float4* q4 = (const float4*)(query + ((size_t)b << 11));
    float sum = 0.f;
    for (int jj = lane; jj < N_/4; jj += 64) {
        float4 qv = q4[jj];
        sum += fexp2(lrelu(ki + qv.x)) + fexp2(lrelu(ki + qv.y))
             + fexp2(lrelu(ki + qv.z)) + fexp2(lrelu(ki + qv.w));
    }
    #pragma unroll
    for (int off = 32; off; off >>= 1) sum += __shfl_down(sum, off);
    if (lane == 0) den[idx] = frcp(sum);
}

// adj[i][j] = 0.125 * sum_b (attn[b][i][j] + attn[b][j][i]); float4 over j
__global__ __launch_bounds__(256) void out_kernel(
    const float* __restrict__ key, const float* __restrict__ query,
    const float* __restrict__ den, float* __restrict__ out)
{
    const int flat = blockIdx.x * 256 + threadIdx.x;   // N*N/4 float4 elems
    const int i  = flat >> 9;            // row (wave-uniform within block)
    const int j0 = (flat & 511) << 2;    // first of 4 cols
    float4 acc = {0.f, 0.f, 0.f, 0.f};
    #pragma unroll
    for (int b = 0; b < B_; ++b) {
        const int bi = (b << 11) + i, bj = (b << 11) + j0;
        const float ki = key[bi], qi = query[bi], di = den[bi];
        const float4 k4 = *(const float4*)&key[bj];
        const float4 q4 = *(const float4*)&query[bj];
        const float4 d4 = *(const float4*)&den[bj];
        acc.x = fmaf(fexp2(lrelu(ki + q4.x)), di, acc.x);
        acc.y = fmaf(fexp2(lrelu(ki + q4.y)), di, acc.y);
        acc.z = fmaf(fexp2(lrelu(ki + q4.z)), di, acc.z);
        acc.w = fmaf(fexp2(lrelu(ki + q4.w)), di, acc.w);
        acc.x = fmaf(fexp2(lrelu(k4.x + qi)), d4.x, acc.x);
        acc.y = fmaf(fexp2(lrelu(k4.y + qi)), d4.y, acc.y);
        acc.z = fmaf(fexp2(lrelu(k4.z + qi)), d4.z, acc.z);
        acc.w = fmaf(fexp2(lrelu(k4.w + qi)), d4.w, acc.w);
    }
    acc.x *= 0.125f; acc.y *= 0.125f; acc.z *= 0.125f; acc.w *= 0.125f;
    ((float4*)out)[flat] = acc;
}

extern "C" void kernel_launch(void* const* d_in, const int* in_sizes, int n_in,
                              void* d_out, int out_size, void* d_ws, size_t ws_size,
                              hipStream_t stream) {
    const float* x    = (const float*)d_in[0];
    const float* w_ih = (const float*)d_in[1];
    const float* w_hh = (const float*)d_in[2];
    const float* b_ih = (const float*)d_in[3];
    const float* b_hh = (const float*)d_in[4];
    const float* wk   = (const float*)d_in[5];
    const float* wq   = (const float*)d_in[6];
    float* out = (float*)d_out;
    float* ws  = (float*)d_ws;

    float* key   = ws;             // 8192
    float* query = ws + 8192;      // 8192
    float* den   = ws + 16384;     // 8192

    gru_kernel<<<M_/16, 64, 0, stream>>>(x, w_ih, w_hh, b_ih, b_hh,
                                         wk, wq, key, query);
    den_kernel<<<M_/4, 256, 0, stream>>>(key, query, den);
    out_kernel<<<(N_*N_/4)/256, 256, 0, stream>>>(key, query, den, out);
}

// Round 16
// 71.824 us; speedup vs baseline: 1.4674x; 1.4674x over previous
//
#include <hip/hip_runtime.h>
#include <math.h>

#define B_ 4
#define T_ 64
#define N_ 2048
#define C_ 32
#define H_ 64
#define M_ (B_*N_)      // 8192
#define SLOPE 0.2f
#define LOG2E 1.44269504088896340736f

typedef __attribute__((ext_vector_type(8))) _Float16 half8;  // 8 f16 (4 VGPRs)
typedef __attribute__((ext_vector_type(4))) float floatx4;   // MFMA acc

#define MFMA16H(a,b,c) __builtin_amdgcn_mfma_f32_16x16x32_f16(a,b,c,0,0,0)

// Barrier without vmcnt drain: LDS visibility via lgkmcnt(0); global prefetch
// loads stay in flight. Uniform control flow at every use.
#define BARRIER() asm volatile("s_waitcnt lgkmcnt(0)\n\ts_barrier" ::: "memory")

__device__ __forceinline__ float lrelu(float v) { return fmaxf(v, SLOPE * v); }
__device__ __forceinline__ float frcp(float x)  { return __builtin_amdgcn_rcpf(x); }
__device__ __forceinline__ float fexp2(float x) { float r; asm("v_exp_f32 %0, %1" : "=v"(r) : "v"(x)); return r; }

__device__ __forceinline__ half8 cvt8h(float4 a, float4 b) {
    half8 h;
    h[0]=(_Float16)a.x; h[1]=(_Float16)a.y; h[2]=(_Float16)a.z; h[3]=(_Float16)a.w;
    h[4]=(_Float16)b.x; h[5]=(_Float16)b.y; h[6]=(_Float16)b.z; h[7]=(_Float16)b.w;
    return h;
}
__device__ __forceinline__ half8 cvt8s(const float* f, float sc) {
    half8 h;
    #pragma unroll
    for (int e = 0; e < 8; ++e) h[e] = (_Float16)(f[e] * sc);
    return h;
}

// ---------------- GRU kernel (R14 structure + split x-phase) ----------------
// 512 blocks x 256 threads (4 waves) = 2 blocks/CU = 2 waves/SIMD (8/CU —
// the max the 512-tile sample parallelism admits; R15 proved fewer waves
// without barriers is worse). Block owns 16 samples; wave w owns gate-cols
// [w*16, w*16+16). h recurrence fp32 in regs; LDS exchange copy fp16
// [2][16][64], swizzle c^((r>>2)<<4). Weights fp16 (gate scales folded).
// 9 MFMA/wave-step: 6 h-phase + 3 x-phase. x-phase split (from R15): R/Z
// issued BEFORE the act chain (MFMA pipe idle there), NI after (WAR on xNI).
__global__ __launch_bounds__(256, 2) void gru_kernel(
    const float* __restrict__ x,      // [B,T,N,C]
    const float* __restrict__ w_ih,   // [192][32]
    const float* __restrict__ w_hh,   // [192][64]
    const float* __restrict__ b_ih,   // [192]
    const float* __restrict__ b_hh,   // [192]
    const float* __restrict__ wk_p,   // [64]
    const float* __restrict__ wq_p,   // [64]
    float* __restrict__ key,          // [M]  (log2e-scaled)
    float* __restrict__ query)        // [M]  (log2e-scaled)
{
    __shared__ __align__(16) _Float16 hh[2][16][64];   // 4 KB
    __shared__ float kq_lds[2][16][4];                 // [k/q][sample][wave]

    const int tid   = threadIdx.x;
    const int lane  = tid & 63;
    const int w     = tid >> 6;        // wave 0..3
    const int col16 = lane & 15;
    const int kgrp  = lane >> 4;       // 0..3

    const int m0 = blockIdx.x * 16;
    const int b  = m0 >> 11;
    const int n0 = m0 & 2047;

    // Gate scales folded into weights/biases:
    //  r: -log2e (r = rcp(1+exp2(aR))); z: +log2e (1-z = rcp(1+exp2(aZ)));
    //  n: 2*log2e (tanh(v) = 1-2*rcp(1+exp2(2*log2e*v)))
    const float gsc[3] = {-LOG2E, LOG2E, 2.f*LOG2E};

    // Weight B-fragments (plain fp16): B[k][col]=w[col][k]
    half8 whhF[3][2];   // [gate][kb]
    half8 wihF[3];
    #pragma unroll
    for (int g = 0; g < 3; ++g) {
        const int rw = g*64 + w*16 + col16;
        #pragma unroll
        for (int kb = 0; kb < 2; ++kb)
            whhF[g][kb] = cvt8s(w_hh + rw*64 + kb*32 + kgrp*8, gsc[g]);
        wihF[g] = cvt8s(w_ih + rw*32 + kgrp*8, gsc[g]);
    }
    const int jcol = w*16 + col16;
    const float br  = -LOG2E     * (b_ih[jcol]    + b_hh[jcol]);
    const float bz  =  LOG2E     * (b_ih[64+jcol] + b_hh[64+jcol]);
    const float bin =  2.f*LOG2E * b_ih[128+jcol];
    const float bhn =  2.f*LOG2E * b_hh[128+jcol];
    const floatx4 bR4  = {br, br, br, br};     // persistent C-operand seeds
    const floatx4 bZ4  = {bz, bz, bz, bz};
    const floatx4 bNI4 = {bin, bin, bin, bin};
    const floatx4 bNH4 = {bhn, bhn, bhn, bhn};

    const float wkj = wk_p[jcol] * LOG2E;      // fused kq projection weights
    const float wqj = wq_p[jcol] * LOG2E;

    // per-lane x source: sample row = col16, channels kgrp*8..+7
    const float* xlane = x + ((size_t)b*T_*N_ + (n0 + col16))*C_ + kgrp*8;
    const int xstride = N_*C_;

    // zero h buf0
    for (int idx = tid; idx < 16*64/2; idx += 256)
        ((int*)&hh[0][0][0])[idx] = 0;

    // ---- prologue: x-phase for step 0; prefetch x(1) ----
    floatx4 xR, xZ, xNI;               // x-projection accs, live across barrier
    {
        const half8 ax = cvt8h(*(const float4*)xlane, *(const float4*)(xlane + 4));
        xR  = MFMA16H(ax, wihF[0], bR4);
        xZ  = MFMA16H(ax, wihF[1], bZ4);
        xNI = MFMA16H(ax, wihF[2], bNI4);
    }
    float4 pAa = *(const float4*)(xlane + xstride);      // x(1) in flight
    float4 pAb = *(const float4*)(xlane + xstride + 4);
    float4 pBa = {0,0,0,0}, pBb = {0,0,0,0};
    BARRIER();

    float hp[4] = {0.f, 0.f, 0.f, 0.f};

// Region T: consume h(T-1) from LDS buf[CUR] + pre-seeded x-accs (step T);
// x(T+1) R/Z MFMAs issued BEFORE act (fill the MFMA pipe while VALU does the
// trans-heavy act chain); xNI(T+1) after act (it reads xNI(T)); then barrier.
#define GRU_STEP(T, CUR, FXa, FXb, GXa, GXb) do {                               \
    const int nxt_ = (CUR) ^ 1;                                                 \
    half8 ah[2];                                                                \
    _Pragma("unroll")                                                           \
    for (int kb = 0; kb < 2; ++kb) {                                            \
        const int ke = (kgrp*8 + kb*32) ^ ((col16 >> 2) << 4);                  \
        ah[kb] = *(const half8*)&hh[CUR][col16][ke];                            \
    }                                                                           \
    /* h-phase: 3 gate chains, depth 2 (kb0 -> kb1); r/z seeded from x-accs */  \
    __builtin_amdgcn_s_setprio(1);                                              \
    floatx4 aR  = MFMA16H(ah[0], whhF[0][0], xR);                               \
    floatx4 aZ  = MFMA16H(ah[0], whhF[1][0], xZ);                               \
    floatx4 aNH = MFMA16H(ah[0], whhF[2][0], bNH4);                             \
    aR  = MFMA16H(ah[1], whhF[0][1], aR);                                       \
    aZ  = MFMA16H(ah[1], whhF[1][1], aZ);                                       \
    aNH = MFMA16H(ah[1], whhF[2][1], aNH);                                      \
    __builtin_amdgcn_s_setprio(0);                                              \
    /* x-phase (T+1) part 1: R/Z (xR/xZ regs dead after h-phase seeds) */       \
    half8 ax_;                                                                  \
    if ((T) + 1 < T_) {                                                         \
        ax_ = cvt8h(FXa, FXb);                                                  \
        xR = MFMA16H(ax_, wihF[0], bR4);                                        \
        xZ = MFMA16H(ax_, wihF[1], bZ4);                                        \
    }                                                                           \
    if ((T) + 2 < T_) {  /* issue load x(T+2) */                                \
        GXa = *(const float4*)(xlane + (size_t)((T)+2) * xstride);              \
        GXb = *(const float4*)(xlane + (size_t)((T)+2) * xstride + 4);          \
    }                                                                           \
    /* activations (exp2-native) + fp16 h store; hp[] stays fp32 */             \
    _Pragma("unroll")                                                           \
    for (int s = 0; s < 4; ++s) {                                               \
        const float tr = frcp(1.f + fexp2(aR[s]));        /* = r   */           \
        const float v  = fmaf(tr, aNH[s], xNI[s]);                              \
        const float tn = frcp(1.f + fexp2(v));                                  \
        const float nn = fmaf(tn, -2.f, 1.f);             /* tanh */            \
        const float tw = frcp(1.f + fexp2(aZ[s]));        /* = 1-z */           \
        const float h  = fmaf(tw, nn - hp[s], hp[s]);                           \
        hp[s] = h;                                                              \
        const int r = kgrp*4 + s;                                               \
        const int c = jcol ^ (kgrp << 4);                                       \
        hh[nxt_][r][c] = (_Float16)h;                                           \
    }                                                                           \
    /* x-phase (T+1) part 2: NI (overlaps store drain / barrier wait) */        \
    if ((T) + 1 < T_) {                                                         \
        xNI = MFMA16H(ax_, wihF[2], bNI4);                                      \
    }                                                                           \
    BARRIER();                                                                  \
} while (0)

    for (int t = 0; t < T_; t += 2) {
        GRU_STEP(t,     0, pAa, pAb, pBa, pBb);
        GRU_STEP(t + 1, 1, pBa, pBb, pAa, pAb);
    }
#undef GRU_STEP

    // ---- fused key/query projection epilogue ----
    float kp[4], qp[4];
    #pragma unroll
    for (int s = 0; s < 4; ++s) { kp[s] = hp[s] * wkj; qp[s] = hp[s] * wqj; }
    #pragma unroll
    for (int mask = 8; mask; mask >>= 1) {
        #pragma unroll
        for (int s = 0; s < 4; ++s) {
            kp[s] += __shfl_xor(kp[s], mask);
            qp[s] += __shfl_xor(qp[s], mask);
        }
    }
    if (col16 == 0) {
        #pragma unroll
        for (int s = 0; s < 4; ++s) {
            kq_lds[0][kgrp*4 + s][w] = kp[s];
            kq_lds[1][kgrp*4 + s][w] = qp[s];
        }
    }
    __syncthreads();
    if (tid < 32) {
        const int smp = tid & 15, sel = tid >> 4;
        const float v = kq_lds[sel][smp][0] + kq_lds[sel][smp][1]
                      + kq_lds[sel][smp][2] + kq_lds[sel][smp][3];
        (sel ? query : key)[m0 + smp] = v;
    }
}

// den stores rcp(sum_j exp2(lrelu(ki+qj))).  No max-shift needed: scores are
// small (|k|,|q| <~ 2) -> exp2 args far inside fp32 range.
__global__ __launch_bounds__(256) void den_kernel(
    const float* __restrict__ key, const float* __restrict__ query,
    float* __restrict__ den)
{
    int idx  = (blockIdx.x * 256 + threadIdx.x) >> 6;   // b*2048 + i
    int lane = threadIdx.x & 63;
    int b    = idx >> 11;
    float ki = key[idx];
    const float4* q4 = (const float4*)(query + ((size_t)b << 11));
    float sum = 0.f;
    for (int jj = lane; jj < N_/4; jj += 64) {
        float4 qv = q4[jj];
        sum += fexp2(lrelu(ki + qv.x)) + fexp2(lrelu(ki + qv.y))
             + fexp2(lrelu(ki + qv.z)) + fexp2(lrelu(ki + qv.w));
    }
    #pragma unroll
    for (int off = 32; off; off >>= 1) sum += __shfl_down(sum, off);
    if (lane == 0) den[idx] = frcp(sum);
}

// adj[i][j] = 0.125 * sum_b (attn[b][i][j] + attn[b][j][i]); float4 over j
__global__ __launch_bounds__(256) void out_kernel(
    const float* __restrict__ key, const float* __restrict__ query,
    const float* __restrict__ den, float* __restrict__ out)
{
    const int flat = blockIdx.x * 256 + threadIdx.x;   // N*N/4 float4 elems
    const int i  = flat >> 9;            // row (wave-uniform within block)
    const int j0 = (flat & 511) << 2;    // first of 4 cols
    float4 acc = {0.f, 0.f, 0.f, 0.f};
    #pragma unroll
    for (int b = 0; b < B_; ++b) {
        const int bi = (b << 11) + i, bj = (b << 11) + j0;
        const float ki = key[bi], qi = query[bi], di = den[bi];
        const float4 k4 = *(const float4*)&key[bj];
        const float4 q4 = *(const float4*)&query[bj];
        const float4 d4 = *(const float4*)&den[bj];
        acc.x = fmaf(fexp2(lrelu(ki + q4.x)), di, acc.x);
        acc.y = fmaf(fexp2(lrelu(ki + q4.y)), di, acc.y);
        acc.z = fmaf(fexp2(lrelu(ki + q4.z)), di, acc.z);
        acc.w = fmaf(fexp2(lrelu(ki + q4.w)), di, acc.w);
        acc.x = fmaf(fexp2(lrelu(k4.x + qi)), d4.x, acc.x);
        acc.y = fmaf(fexp2(lrelu(k4.y + qi)), d4.y, acc.y);
        acc.z = fmaf(fexp2(lrelu(k4.z + qi)), d4.z, acc.z);
        acc.w = fmaf(fexp2(lrelu(k4.w + qi)), d4.w, acc.w);
    }
    acc.x *= 0.125f; acc.y *= 0.125f; acc.z *= 0.125f; acc.w *= 0.125f;
    ((float4*)out)[flat] = acc;
}

extern "C" void kernel_launch(void* const* d_in, const int* in_sizes, int n_in,
                              void* d_out, int out_size, void* d_ws, size_t ws_size,
                              hipStream_t stream) {
    const float* x    = (const float*)d_in[0];
    const float* w_ih = (const float*)d_in[1];
    const float* w_hh = (const float*)d_in[2];
    const float* b_ih = (const float*)d_in[3];
    const float* b_hh = (const float*)d_in[4];
    const float* wk   = (const float*)d_in[5];
    const float* wq   = (const float*)d_in[6];
    float* out = (float*)d_out;
    float* ws  = (float*)d_ws;

    float* key   = ws;             // 8192
    float* query = ws + 8192;      // 8192
    float* den   = ws + 16384;     // 8192

    gru_kernel<<<M_/16, 256, 0, stream>>>(x, w_ih, w_hh, b_ih, b_hh,
                                          wk, wq, key, query);
    den_kernel<<<M_/4, 256, 0, stream>>>(key, query, den);
    out_kernel<<<(N_*N_/4)/256, 256, 0, stream>>>(key, query, den, out);
}